// Round 5
// baseline (588.987 us; speedup 1.0000x reference)
//
#include <hip/hip_runtime.h>
#include <stdint.h>

#define CIN 64
#define COUT 128
#define BLOCK 256
#define WPB 4                 // waves per block
#define WT_STRIDE 136         // ushorts per W^T row (272 B = 4-bank rotate)
#define SEG_STRIDE 144        // bytes per staged (tap,row) segment (4-bank rotate, 16B-aligned)
// per-wave stage: 32 segs * 144 B = 4608 B; block total LDS = 34816 + 18432 + 1024 = 54272 B
// -> 3 blocks/CU, 12 waves/CU

typedef __attribute__((ext_vector_type(8))) __bf16 bf16x8;
typedef __attribute__((ext_vector_type(8))) unsigned short ushort8;
typedef __attribute__((ext_vector_type(4))) float f32x4;

__device__ __forceinline__ unsigned short f2bf(float f) {
    // round-to-nearest-even fp32 -> bf16
    uint32_t u = __float_as_uint(f);
    u = (u + 0x7FFFu + ((u >> 16) & 1u)) >> 16;
    return (unsigned short)u;
}

// Build inverse map: for each input row i, record i+1 at inv[kz][out_ids[i]].
// At most one input per (output, tap) pair -> plain stores, no atomics needed.
__global__ void scatter_inv_kernel(const int* __restrict__ kz,
                                   const int* __restrict__ oid,
                                   int* __restrict__ inv0,
                                   int* __restrict__ inv1,
                                   int n) {
    int i = blockIdx.x * blockDim.x + threadIdx.x;
    if (i < n) {
        int o = oid[i];
        if (kz[i] == 0) inv0[o] = i + 1;
        else            inv1[o] = i + 1;
    }
}

// One wave == one 16-row output tile, grid-stride, no inter-wave barriers in
// the loop. DEPTH-2 software pipeline: two register gather sets (A/B, loop
// unrolled by 2 so all array indices are static), inv indices prefetched 4
// tiles ahead. Coalesced 256-B row gathers -> bf16 -> wave-private LDS bounce
// (same-wave DS in-order, no barrier) -> MFMA fragment reads.
// Output stores are NONTEMPORAL: feat (153.6 MB) fits in the 256 MB LLC, and
// keeping the 307 MB write stream out of the LLC keeps feat resident across
// dispatches (read latency ~L2/LLC instead of HBM).
__launch_bounds__(BLOCK, 3)
__global__ void spconv_bn_relu_kernel(const float* __restrict__ feat,
                                      const float* __restrict__ W,
                                      const float* __restrict__ gamma,
                                      const float* __restrict__ beta,
                                      const float* __restrict__ rmean,
                                      const float* __restrict__ rvar,
                                      const int* __restrict__ inv0,
                                      const int* __restrict__ inv1,
                                      const int* __restrict__ n_out_p,
                                      float* __restrict__ out,
                                      int N, int num_wtiles) {
    __shared__ unsigned short lds_wT[COUT * WT_STRIDE];                      // 34816 B
    __shared__ __align__(16) unsigned char lds_stage[WPB * 32 * SEG_STRIDE]; // 18432 B
    __shared__ __align__(16) float lds_scale[COUT];
    __shared__ __align__(16) float lds_bias[COUT];

    const int tid = threadIdx.x;
    const int nout = *n_out_p;

    // ---- phase 0 (once per block): Wcat -> LDS, transposed, bf16 ----
    // W global layout: [tap][cin][cout] flat = (tap*64+cin)*128 + cout = k*128 + n
    const float4* W4 = (const float4*)W;
    #pragma unroll
    for (int u = 0; u < 16; ++u) {
        int flat4 = u * BLOCK + tid;   // 0..4095 float4s
        int n4 = flat4 & 31;           // float4 index within a 128-cout row
        int k  = flat4 >> 5;           // 0..127 = tap*64+cin
        float4 v = W4[flat4];
        int nb = n4 * 4;
        lds_wT[(nb + 0) * WT_STRIDE + k] = f2bf(v.x);
        lds_wT[(nb + 1) * WT_STRIDE + k] = f2bf(v.y);
        lds_wT[(nb + 2) * WT_STRIDE + k] = f2bf(v.z);
        lds_wT[(nb + 3) * WT_STRIDE + k] = f2bf(v.w);
    }
    if (tid < COUT) {
        float s = gamma[tid] * rsqrtf(rvar[tid] + 1e-5f);
        lds_scale[tid] = s;
        lds_bias[tid]  = fmaf(-rmean[tid], s, beta[tid]);
    }
    __syncthreads();   // only barrier in the kernel

    const float4* feat4 = (const float4*)feat;
    const int wave   = tid >> 6;
    const int lane   = tid & 63;
    const int lrow   = lane & 15;
    const int quad   = lane >> 4;
    const int lseg   = lane >> 3;   // 0..7: segment within a load round
    const int lchunk = lane & 7;    // 0..7: 32-B chunk within the 256-B row

    unsigned char* stg = lds_stage + wave * (32 * SEG_STRIDE);

    const int gwave   = blockIdx.x * WPB + wave;
    const int wstride = gridDim.x * WPB;

#define LOAD_INV(WT, J0, J1) do {                                         \
        (J0) = 0; (J1) = 0;                                               \
        if ((WT) < num_wtiles) {                                          \
            int _r = (WT) * 16 + lrow;                                    \
            if (_r < N) { (J0) = inv0[_r]; (J1) = inv1[_r]; }             \
        }                                                                 \
    } while (0)

#define ISSUE_GATHER(J0, J1, GA, GB) do {                                 \
        _Pragma("unroll")                                                 \
        for (int _r = 0; _r < 4; ++_r) {                                  \
            int _seg = _r * 8 + lseg;                                     \
            int _rs  = _seg & 15;                                         \
            int _idx = (_seg & 16) ? __shfl((J1), _rs, 64)                \
                                   : __shfl((J0), _rs, 64);               \
            GA[_r] = make_float4(0.f, 0.f, 0.f, 0.f);                     \
            GB[_r] = GA[_r];                                              \
            if (_idx > 0) {                                               \
                const float4* _p = feat4 + (size_t)(_idx - 1) * 16 + lchunk * 2; \
                GA[_r] = _p[0];                                           \
                GB[_r] = _p[1];                                           \
            }                                                             \
        }                                                                 \
    } while (0)

#define STAGE(GA, GB) do {                                                \
        _Pragma("unroll")                                                 \
        for (int _r = 0; _r < 4; ++_r) {                                  \
            int _seg = _r * 8 + lseg;                                     \
            ushort8 _u;                                                   \
            _u[0] = f2bf(GA[_r].x); _u[1] = f2bf(GA[_r].y);               \
            _u[2] = f2bf(GA[_r].z); _u[3] = f2bf(GA[_r].w);               \
            _u[4] = f2bf(GB[_r].x); _u[5] = f2bf(GB[_r].y);               \
            _u[6] = f2bf(GB[_r].z); _u[7] = f2bf(GB[_r].w);               \
            *(ushort8*)(stg + _seg * SEG_STRIDE + lchunk * 16) = _u;      \
        }                                                                 \
    } while (0)

#define COMPUTE_STORE(WT) do {                                            \
        const int _row = (WT) * 16 + lrow;                                \
        bf16x8 _af[4];                                                    \
        _Pragma("unroll")                                                 \
        for (int _s = 0; _s < 4; ++_s) {                                  \
            int _sg = (_s >> 1) * 16 + lrow;                              \
            _af[_s] = __builtin_bit_cast(bf16x8,                          \
                *(const ushort8*)(stg + _sg * SEG_STRIDE + (_s & 1) * 64 + quad * 16)); \
        }                                                                 \
        _Pragma("unroll")                                                 \
        for (int _c = 0; _c < 8; ++_c) {                                  \
            const unsigned short* _bb = &lds_wT[(_c * 16 + lrow) * WT_STRIDE + quad * 8]; \
            f32x4 _acc = {0.f, 0.f, 0.f, 0.f};                            \
            _Pragma("unroll")                                             \
            for (int _s = 0; _s < 4; ++_s) {                              \
                bf16x8 _wf = __builtin_bit_cast(bf16x8, *(const ushort8*)(_bb + _s * 32)); \
                _acc = __builtin_amdgcn_mfma_f32_16x16x32_bf16(_wf, _af[_s], _acc, 0, 0, 0); \
            }                                                             \
            if (_row < N) {                                               \
                const int _col = _c * 16 + quad * 4;                      \
                f32x4 _o4 = {0.f, 0.f, 0.f, 0.f};                         \
                if (_row < nout) {                                        \
                    f32x4 _sc = *(const f32x4*)&lds_scale[_col];          \
                    f32x4 _bi = *(const f32x4*)&lds_bias[_col];           \
                    _o4[0] = fmaxf(fmaf(_acc[0], _sc[0], _bi[0]), 0.f);   \
                    _o4[1] = fmaxf(fmaf(_acc[1], _sc[1], _bi[1]), 0.f);   \
                    _o4[2] = fmaxf(fmaf(_acc[2], _sc[2], _bi[2]), 0.f);   \
                    _o4[3] = fmaxf(fmaf(_acc[3], _sc[3], _bi[3]), 0.f);   \
                }                                                         \
                __builtin_nontemporal_store(_o4,                          \
                    (f32x4*)&out[(size_t)_row * COUT + _col]);            \
            }                                                             \
        }                                                                 \
    } while (0)

    // ---- depth-2 pipeline prologue ----
    int wt = gwave;
    int jA0, jA1, jB0, jB1, pA0, pA1, pB0, pB1;
    float4 gaA[4], gbA[4], gaB[4], gbB[4];

    LOAD_INV(wt, jA0, jA1);
    ISSUE_GATHER(jA0, jA1, gaA, gbA);              // gathers(t) in flight
    LOAD_INV(wt + wstride, jB0, jB1);
    ISSUE_GATHER(jB0, jB1, gaB, gbB);              // gathers(t+1) in flight
    LOAD_INV(wt + 2 * wstride, pA0, pA1);          // inv(t+2) in flight
    LOAD_INV(wt + 3 * wstride, pB0, pB1);          // inv(t+3) in flight

    for (; wt < num_wtiles; wt += 2 * wstride) {
        // ---- even half: tile wt (set A) ----
        STAGE(gaA, gbA);                           // waits only on A-set loads
        ISSUE_GATHER(pA0, pA1, gaA, gbA);          // gathers(t+2): in flight through MFMA
        LOAD_INV(wt + 4 * wstride, pA0, pA1);      // inv(t+4)
        COMPUTE_STORE(wt);

        // ---- odd half: tile wt+wstride (set B) ----
        int wtB = wt + wstride;
        if (wtB < num_wtiles) {
            STAGE(gaB, gbB);
            ISSUE_GATHER(pB0, pB1, gaB, gbB);      // gathers(t+3)
            LOAD_INV(wtB + 4 * wstride, pB0, pB1); // inv(t+5)
            COMPUTE_STORE(wtB);
        }
    }

#undef LOAD_INV
#undef ISSUE_GATHER
#undef STAGE
#undef COMPUTE_STORE
}

extern "C" void kernel_launch(void* const* d_in, const int* in_sizes, int n_in,
                              void* d_out, int out_size, void* d_ws, size_t ws_size,
                              hipStream_t stream) {
    const float* feat  = (const float*)d_in[0];
    const float* W     = (const float*)d_in[1];
    const float* gamma = (const float*)d_in[2];
    const float* beta  = (const float*)d_in[3];
    const float* rmean = (const float*)d_in[4];
    const float* rvar  = (const float*)d_in[5];
    const int*   kz    = (const int*)d_in[6];
    const int*   oid   = (const int*)d_in[7];
    const int*   noutp = (const int*)d_in[8];
    float* out = (float*)d_out;

    const int N = in_sizes[6];   // 600000

    int* inv0 = (int*)d_ws;
    int* inv1 = inv0 + N;

    // inv maps: 0 = no contributor (ws is re-poisoned each call, so always clear)
    (void)hipMemsetAsync(d_ws, 0, (size_t)2 * N * sizeof(int), stream);

    int sb = (N + 255) / 256;
    scatter_inv_kernel<<<sb, 256, 0, stream>>>(kz, oid, inv0, inv1, N);

    int num_wtiles = (N + 15) / 16;                       // 37500 wave-tiles
    int nblocks = (num_wtiles + WPB - 1) / WPB;
    int grid = nblocks < 1024 ? nblocks : 1024;           // 3 resident/CU + backfill
    spconv_bn_relu_kernel<<<grid, BLOCK, 0, stream>>>(
        feat, W, gamma, beta, rmean, rvar, inv0, inv1, noutp, out, N, num_wtiles);
}

// Round 6
// 574.380 us; speedup vs baseline: 1.0254x; 1.0254x over previous
//
#include <hip/hip_runtime.h>
#include <stdint.h>

#define CIN 64
#define COUT 128
#define BLOCK 256
#define WPB 4                 // waves per block
#define WT_STRIDE 136         // ushorts per W^T row (272 B = 4-bank rotate)
#define SEG_STRIDE 144        // bytes per staged (tap,row) segment (4-bank rotate, 16B-aligned)
// per-wave stage: 32 segs * 144 B = 4608 B; block total LDS = 34816 + 18432 + 1024 = 54272 B
// -> 3 blocks/CU, 12 waves/CU

typedef __attribute__((ext_vector_type(8))) __bf16 bf16x8;
typedef __attribute__((ext_vector_type(8))) unsigned short ushort8;
typedef __attribute__((ext_vector_type(4))) float f32x4;

__device__ __forceinline__ unsigned short f2bf(float f) {
    // round-to-nearest-even fp32 -> bf16
    uint32_t u = __float_as_uint(f);
    u = (u + 0x7FFFu + ((u >> 16) & 1u)) >> 16;
    return (unsigned short)u;
}

// Build inverse map: for each input row i, record i+1 at inv[kz][out_ids[i]].
// At most one input per (output, tap) pair -> plain stores, no atomics needed.
__global__ void scatter_inv_kernel(const int* __restrict__ kz,
                                   const int* __restrict__ oid,
                                   int* __restrict__ inv0,
                                   int* __restrict__ inv1,
                                   int n) {
    int i = blockIdx.x * blockDim.x + threadIdx.x;
    if (i < n) {
        int o = oid[i];
        if (kz[i] == 0) inv0[o] = i + 1;
        else            inv1[o] = i + 1;
    }
}

// One wave == one 16-row output tile, grid-stride, no inter-wave barriers in
// the loop. DEPTH-2 software pipeline: two register gather sets (A/B, loop
// unrolled by 2 so all array indices are static), inv indices prefetched 4
// tiles ahead. Coalesced 256-B row gathers -> bf16 -> wave-private LDS bounce
// (same-wave DS in-order, no barrier) -> MFMA fragment reads.
// Output stores are PLAIN cached float4 stores: L2 write-combines the 8
// partial 64-B writes per 512-B output row into full lines (nontemporal
// stores measured +300 MB of RMW traffic in round 5 -- do not bypass L2).
__launch_bounds__(BLOCK, 3)
__global__ void spconv_bn_relu_kernel(const float* __restrict__ feat,
                                      const float* __restrict__ W,
                                      const float* __restrict__ gamma,
                                      const float* __restrict__ beta,
                                      const float* __restrict__ rmean,
                                      const float* __restrict__ rvar,
                                      const int* __restrict__ inv0,
                                      const int* __restrict__ inv1,
                                      const int* __restrict__ n_out_p,
                                      float* __restrict__ out,
                                      int N, int num_wtiles) {
    __shared__ unsigned short lds_wT[COUT * WT_STRIDE];                      // 34816 B
    __shared__ __align__(16) unsigned char lds_stage[WPB * 32 * SEG_STRIDE]; // 18432 B
    __shared__ __align__(16) float lds_scale[COUT];
    __shared__ __align__(16) float lds_bias[COUT];

    const int tid = threadIdx.x;
    const int nout = *n_out_p;

    // ---- phase 0 (once per block): Wcat -> LDS, transposed, bf16 ----
    // W global layout: [tap][cin][cout] flat = (tap*64+cin)*128 + cout = k*128 + n
    const float4* W4 = (const float4*)W;
    #pragma unroll
    for (int u = 0; u < 16; ++u) {
        int flat4 = u * BLOCK + tid;   // 0..4095 float4s
        int n4 = flat4 & 31;           // float4 index within a 128-cout row
        int k  = flat4 >> 5;           // 0..127 = tap*64+cin
        float4 v = W4[flat4];
        int nb = n4 * 4;
        lds_wT[(nb + 0) * WT_STRIDE + k] = f2bf(v.x);
        lds_wT[(nb + 1) * WT_STRIDE + k] = f2bf(v.y);
        lds_wT[(nb + 2) * WT_STRIDE + k] = f2bf(v.z);
        lds_wT[(nb + 3) * WT_STRIDE + k] = f2bf(v.w);
    }
    if (tid < COUT) {
        float s = gamma[tid] * rsqrtf(rvar[tid] + 1e-5f);
        lds_scale[tid] = s;
        lds_bias[tid]  = fmaf(-rmean[tid], s, beta[tid]);
    }
    __syncthreads();   // only barrier in the kernel

    const float4* feat4 = (const float4*)feat;
    const int wave   = tid >> 6;
    const int lane   = tid & 63;
    const int lrow   = lane & 15;
    const int quad   = lane >> 4;
    const int lseg   = lane >> 3;   // 0..7: segment within a load round
    const int lchunk = lane & 7;    // 0..7: 32-B chunk within the 256-B row

    unsigned char* stg = lds_stage + wave * (32 * SEG_STRIDE);

    const int gwave   = blockIdx.x * WPB + wave;
    const int wstride = gridDim.x * WPB;

#define LOAD_INV(WT, J0, J1) do {                                         \
        (J0) = 0; (J1) = 0;                                               \
        if ((WT) < num_wtiles) {                                          \
            int _r = (WT) * 16 + lrow;                                    \
            if (_r < N) { (J0) = inv0[_r]; (J1) = inv1[_r]; }             \
        }                                                                 \
    } while (0)

#define ISSUE_GATHER(J0, J1, GA, GB) do {                                 \
        _Pragma("unroll")                                                 \
        for (int _r = 0; _r < 4; ++_r) {                                  \
            int _seg = _r * 8 + lseg;                                     \
            int _rs  = _seg & 15;                                         \
            int _idx = (_seg & 16) ? __shfl((J1), _rs, 64)                \
                                   : __shfl((J0), _rs, 64);               \
            GA[_r] = make_float4(0.f, 0.f, 0.f, 0.f);                     \
            GB[_r] = GA[_r];                                              \
            if (_idx > 0) {                                               \
                const float4* _p = feat4 + (size_t)(_idx - 1) * 16 + lchunk * 2; \
                GA[_r] = _p[0];                                           \
                GB[_r] = _p[1];                                           \
            }                                                             \
        }                                                                 \
    } while (0)

#define STAGE(GA, GB) do {                                                \
        _Pragma("unroll")                                                 \
        for (int _r = 0; _r < 4; ++_r) {                                  \
            int _seg = _r * 8 + lseg;                                     \
            ushort8 _u;                                                   \
            _u[0] = f2bf(GA[_r].x); _u[1] = f2bf(GA[_r].y);               \
            _u[2] = f2bf(GA[_r].z); _u[3] = f2bf(GA[_r].w);               \
            _u[4] = f2bf(GB[_r].x); _u[5] = f2bf(GB[_r].y);               \
            _u[6] = f2bf(GB[_r].z); _u[7] = f2bf(GB[_r].w);               \
            *(ushort8*)(stg + _seg * SEG_STRIDE + lchunk * 16) = _u;      \
        }                                                                 \
    } while (0)

#define COMPUTE_STORE(WT) do {                                            \
        const int _row = (WT) * 16 + lrow;                                \
        bf16x8 _af[4];                                                    \
        _Pragma("unroll")                                                 \
        for (int _s = 0; _s < 4; ++_s) {                                  \
            int _sg = (_s >> 1) * 16 + lrow;                              \
            _af[_s] = __builtin_bit_cast(bf16x8,                          \
                *(const ushort8*)(stg + _sg * SEG_STRIDE + (_s & 1) * 64 + quad * 16)); \
        }                                                                 \
        _Pragma("unroll")                                                 \
        for (int _c = 0; _c < 8; ++_c) {                                  \
            const unsigned short* _bb = &lds_wT[(_c * 16 + lrow) * WT_STRIDE + quad * 8]; \
            f32x4 _acc = {0.f, 0.f, 0.f, 0.f};                            \
            _Pragma("unroll")                                             \
            for (int _s = 0; _s < 4; ++_s) {                              \
                bf16x8 _wf = __builtin_bit_cast(bf16x8, *(const ushort8*)(_bb + _s * 32)); \
                _acc = __builtin_amdgcn_mfma_f32_16x16x32_bf16(_wf, _af[_s], _acc, 0, 0, 0); \
            }                                                             \
            if (_row < N) {                                               \
                const int _col = _c * 16 + quad * 4;                      \
                float4 _o4 = make_float4(0.f, 0.f, 0.f, 0.f);             \
                if (_row < nout) {                                        \
                    f32x4 _sc = *(const f32x4*)&lds_scale[_col];          \
                    f32x4 _bi = *(const f32x4*)&lds_bias[_col];           \
                    _o4.x = fmaxf(fmaf(_acc[0], _sc[0], _bi[0]), 0.f);    \
                    _o4.y = fmaxf(fmaf(_acc[1], _sc[1], _bi[1]), 0.f);    \
                    _o4.z = fmaxf(fmaf(_acc[2], _sc[2], _bi[2]), 0.f);    \
                    _o4.w = fmaxf(fmaf(_acc[3], _sc[3], _bi[3]), 0.f);    \
                }                                                         \
                *(float4*)&out[(size_t)_row * COUT + _col] = _o4;         \
            }                                                             \
        }                                                                 \
    } while (0)

    // ---- depth-2 pipeline prologue ----
    int wt = gwave;
    int jA0, jA1, jB0, jB1, pA0, pA1, pB0, pB1;
    float4 gaA[4], gbA[4], gaB[4], gbB[4];

    LOAD_INV(wt, jA0, jA1);
    ISSUE_GATHER(jA0, jA1, gaA, gbA);              // gathers(t) in flight
    LOAD_INV(wt + wstride, jB0, jB1);
    ISSUE_GATHER(jB0, jB1, gaB, gbB);              // gathers(t+1) in flight
    LOAD_INV(wt + 2 * wstride, pA0, pA1);          // inv(t+2) in flight
    LOAD_INV(wt + 3 * wstride, pB0, pB1);          // inv(t+3) in flight

    for (; wt < num_wtiles; wt += 2 * wstride) {
        // ---- even half: tile wt (set A) ----
        STAGE(gaA, gbA);                           // waits only on A-set loads
        ISSUE_GATHER(pA0, pA1, gaA, gbA);          // gathers(t+2): in flight through MFMA
        LOAD_INV(wt + 4 * wstride, pA0, pA1);      // inv(t+4)
        COMPUTE_STORE(wt);

        // ---- odd half: tile wt+wstride (set B) ----
        int wtB = wt + wstride;
        if (wtB < num_wtiles) {
            STAGE(gaB, gbB);
            ISSUE_GATHER(pB0, pB1, gaB, gbB);      // gathers(t+3)
            LOAD_INV(wtB + 4 * wstride, pB0, pB1); // inv(t+5)
            COMPUTE_STORE(wtB);
        }
    }

#undef LOAD_INV
#undef ISSUE_GATHER
#undef STAGE
#undef COMPUTE_STORE
}

extern "C" void kernel_launch(void* const* d_in, const int* in_sizes, int n_in,
                              void* d_out, int out_size, void* d_ws, size_t ws_size,
                              hipStream_t stream) {
    const float* feat  = (const float*)d_in[0];
    const float* W     = (const float*)d_in[1];
    const float* gamma = (const float*)d_in[2];
    const float* beta  = (const float*)d_in[3];
    const float* rmean = (const float*)d_in[4];
    const float* rvar  = (const float*)d_in[5];
    const int*   kz    = (const int*)d_in[6];
    const int*   oid   = (const int*)d_in[7];
    const int*   noutp = (const int*)d_in[8];
    float* out = (float*)d_out;

    const int N = in_sizes[6];   // 600000

    int* inv0 = (int*)d_ws;
    int* inv1 = inv0 + N;

    // inv maps: 0 = no contributor (ws is re-poisoned each call, so always clear)
    (void)hipMemsetAsync(d_ws, 0, (size_t)2 * N * sizeof(int), stream);

    int sb = (N + 255) / 256;
    scatter_inv_kernel<<<sb, 256, 0, stream>>>(kz, oid, inv0, inv1, N);

    int num_wtiles = (N + 15) / 16;                       // 37500 wave-tiles
    int nblocks = (num_wtiles + WPB - 1) / WPB;
    int grid = nblocks < 1024 ? nblocks : 1024;           // 3 resident/CU + backfill
    spconv_bn_relu_kernel<<<grid, BLOCK, 0, stream>>>(
        feat, W, gamma, beta, rmean, rvar, inv0, inv1, noutp, out, N, num_wtiles);
}